// Round 2
// baseline (1040.826 us; speedup 1.0000x reference)
//
#include <hip/hip_runtime.h>

// BioRNN fp32: T=1000, B=4096, H=50, IN=8, OUT=6.
//   r = relu(h);  y_t = r@W_out^T + b_out;  h += DT*(-h + x@W_in^T + r@W_rec^T + bias)
//
// R=4 rows/lane design. Block = 128 thr: b = tid&7 (batch slot), jg = tid>>3
// (0..15 row group). Lane (b,jg) owns rows {jg, jg+14, jg+28, jg+42} (jg<14);
// jg=14,15 get zero weight rows 56..63 -> compute harmless zeros.
// Rows 0..49 = hidden (W_rec+W_in+bias), 50..55 = output (W_out, b_out folded).
// Each lane's row 3 is the only possible y-row (jg in 8..13 -> out col jg-8).
//
// Weights: staged once into a zero-padded LDS table Wall[64][52] (+WiA, biasA)
// -- uniform, branch-free -- then loaded to VGPRs as float4 wf[4][13].
// __launch_bounds__(128,1) gives the allocator a 512-VGPR budget so the ~280
// live regs stay register-resident (round-1 failure mode: VGPR=92 => compiler
// sank weight loads into the loop).
//
// r exchange: double-buffered r_lds[2][8][52] (52-float stride: b*52 mod 32
// distinct per b -> conflict-free b128 reads). ONE barrier per step; the
// double buffer makes the write->read WAR safe without a second barrier.
// Per-CU LDS pipe: 4 waves x 13 ds_read_b128 ~ 710 cyc/step (the new limit).

#define T_STEPS 1000
#define BATCH   4096
#define INSZ    8
#define H       50
#define NROWS   56
#define OUTSZ   6
#define DT      0.1f
#define BPB     8
#define KP      52      // padded r stride: 13 float4; k=50,51 zero pad
#define NWROWS  64      // staged rows incl. zero rows 56..63

__global__ __launch_bounds__(128, 1)
void biornn_kernel(const float* __restrict__ xg,   // (T, B, INSZ)
                   const float* __restrict__ Wi,   // (H, INSZ)
                   const float* __restrict__ Wr,   // (H, H)
                   const float* __restrict__ bs,   // (H)
                   const float* __restrict__ Wo,   // (OUTSZ, H)
                   const float* __restrict__ bo,   // (OUTSZ)
                   float* __restrict__ out)        // (T, B, OUTSZ)
{
    __shared__ __align__(16) float Wall[NWROWS][KP];   // 13.0 KB
    __shared__ float WiA[NWROWS][INSZ];                // 2.0 KB
    __shared__ float biasA[NWROWS];
    __shared__ __align__(16) float r_lds[2][BPB][KP];  // 3.3 KB

    const int tid = threadIdx.x;

    // ---- stage zero-padded weight tables (once) ----
    for (int idx = tid; idx < NWROWS * KP; idx += 128) {
        const int j = idx / KP, k = idx - j * KP;
        float v = 0.f;
        if (k < H) {
            if (j < H)          v = Wr[j * H + k];
            else if (j < NROWS) v = Wo[(j - H) * H + k];
        }
        Wall[j][k] = v;
    }
    for (int idx = tid; idx < NWROWS * INSZ; idx += 128) {
        const int j = idx >> 3, i = idx & 7;
        WiA[j][i] = (j < H) ? Wi[j * INSZ + i] : 0.f;
    }
    if (tid < NWROWS)
        biasA[tid] = (tid < H) ? bs[tid] : bo[tid - H];
    // zero the r pads (k=50,51) of both buffers; never written afterwards
    if (tid < 2 * BPB) {
        r_lds[tid >> 3][tid & 7][H]     = 0.f;
        r_lds[tid >> 3][tid & 7][H + 1] = 0.f;
    }
    __syncthreads();

    const int b  = tid & (BPB - 1);
    const int jg = tid >> 3;              // 0..15

    // ---- per-lane row set -> registers ----
    int   rowm[4];
    float4 wf[4][13];
    float wi[4][INSZ];
    float biasr[4];
    bool  ish[4];
#pragma unroll
    for (int m = 0; m < 4; ++m) {
        rowm[m] = (jg < 14) ? (jg + 14 * m) : (NROWS + m + ((jg - 14) << 2));
        ish[m]  = (rowm[m] < H);
#pragma unroll
        for (int c = 0; c < 13; ++c)
            wf[m][c] = *(const float4*)&Wall[rowm[m]][4 * c];
#pragma unroll
        for (int i = 0; i < INSZ; ++i)
            wi[m][i] = WiA[rowm[m]][i];
        biasr[m] = biasA[rowm[m]];
    }
    const bool isy3 = (rowm[3] >= H) && (rowm[3] < NROWS);   // jg in 8..13

    // ---- per-lane state ----
    const int b_glob = blockIdx.x * BPB + b;
    float h[4] = {0.f, 0.f, 0.f, 0.f};

    const float* xp = xg + (size_t)b_glob * INSZ;
    float4 xa = *(const float4*)(xp);
    float4 xb = *(const float4*)(xp + 4);
    xp += (size_t)BATCH * INSZ;

    // y pointer (only dereferenced when isy3): column = rowm[3]-50 = jg-8
    float* yp = out + (size_t)b_glob * OUTSZ + (isy3 ? (jg - 8) : 0);

    for (int t = 0; t < T_STEPS; ++t) {
        const int cur = t & 1;

        // publish r = relu(h) for owned hidden rows (ish guards feeders/y-rows)
#pragma unroll
        for (int m = 0; m < 4; ++m) {
            const float rr = fmaxf(h[m], 0.f);
            if (ish[m]) r_lds[cur][b][rowm[m]] = rr;
        }
        __syncthreads();   // the only barrier per step

        float acc[4] = {biasr[0], biasr[1], biasr[2], biasr[3]};
#pragma unroll
        for (int c = 0; c < 13; ++c) {
            const float4 rv = *(const float4*)&r_lds[cur][b][4 * c];
#pragma unroll
            for (int m = 0; m < 4; ++m) {
                acc[m] = fmaf(rv.x, wf[m][c].x, acc[m]);
                acc[m] = fmaf(rv.y, wf[m][c].y, acc[m]);
                acc[m] = fmaf(rv.z, wf[m][c].z, acc[m]);
                acc[m] = fmaf(rv.w, wf[m][c].w, acc[m]);
            }
        }
        const float xs[8] = {xa.x, xa.y, xa.z, xa.w, xb.x, xb.y, xb.z, xb.w};
#pragma unroll
        for (int i = 0; i < INSZ; ++i)
#pragma unroll
            for (int m = 0; m < 4; ++m)
                acc[m] = fmaf(xs[i], wi[m][i], acc[m]);

        // prefetch x[t+1] (wait lands next iteration)
        if (t + 1 < T_STEPS) {
            xa = *(const float4*)(xp);
            xb = *(const float4*)(xp + 4);
            xp += (size_t)BATCH * INSZ;
        }

        // h <- h + DT*(acc - h); harmless on y/feeder rows
#pragma unroll
        for (int m = 0; m < 4; ++m)
            h[m] = fmaf(DT, acc[m] - h[m], h[m]);

        if (isy3) *yp = acc[3];
        yp += BATCH * OUTSZ;
    }
}

extern "C" void kernel_launch(void* const* d_in, const int* in_sizes, int n_in,
                              void* d_out, int out_size, void* d_ws, size_t ws_size,
                              hipStream_t stream)
{
    const float* xg = (const float*)d_in[0];  // input_seq (1000,4096,8)
    const float* Wi = (const float*)d_in[1];  // W_in (50,8)
    const float* Wr = (const float*)d_in[2];  // W_rec (50,50)
    const float* bs = (const float*)d_in[3];  // bias (50)
    const float* Wo = (const float*)d_in[4];  // W_out_w (6,50)
    const float* bo = (const float*)d_in[5];  // W_out_b (6)
    float* outp = (float*)d_out;              // (1000,4096,6)

    dim3 grid(BATCH / BPB);   // 512 blocks
    dim3 block(128);          // 2 waves
    hipLaunchKernelGGL(biornn_kernel, grid, block, 0, stream,
                       xg, Wi, Wr, bs, Wo, bo, outp);
}